// Round 6
// baseline (86.699 us; speedup 1.0000x reference)
//
#include <hip/hip_runtime.h>

// ============ DIAGNOSTIC ROUND: core compute repeated REPS times ============
// Slope (dur - 14.2)/(REPS-1) isolates per-pass compute cost from fixed
// overhead; large dur also pushes this kernel into rocprof top-5 so we
// finally get its counters. Semantics unchanged (idempotent repeats).
#define REPS 16

// Problem constants (fixed by setup_inputs / reference)
#define NPG    32768          // nodes per batch group
#define NTOT   131072         // B * NPG
#define MAXN   16             // max neighbors kept
#define RAD2   49             // RADIUS_PX^2, RADIUS_PX = int(0.01*640+1) = 7
#define DTMAX  10000u         // int(0.01 * 1e6)
#define NPB    64             // nodes per block
#define QW     64             // offsets per quarter-window (256 = 4 x 64)

__global__ __launch_bounds__(256, 8)
void tgn_edges_kernel(const float* __restrict__ pos, int* __restrict__ out) {
    __shared__ int           sp_xy[320];             // packed (x | y<<16) for nodes [b0-256, b0+64)
    __shared__ int           sp_t[320];              // t for same nodes
    __shared__ unsigned char qslot[NPB][4][MAXN];    // per-(node,quarter) matches: stores off-1
    __shared__ unsigned char scnt[NPB][4];           // per-(node,quarter) match count (capped 16)
    __shared__ int           fin[NPB][MAXN];         // final src rows for this block

    const int tid = threadIdx.x;
    const int b0  = blockIdx.x * NPB;

    // ---- Stage + convert nodes [b0-256, b0+64) into LDS (320 nodes, 256 threads).
    #pragma unroll
    for (int s = 0; s < 2; ++s) {
        const int idx = s * 256 + tid;
        if (s == 0 || tid < NPB) {
            const int node = b0 - 256 + idx;
            int vxy = 0, vt = 0;
            if (node >= 0) {
                const float x  = pos[3 * node + 0];
                const float y  = pos[3 * node + 1];
                const float tt = pos[3 * node + 2];
                // Must bit-match numpy float32: int32(denorm*pos + 0.001).
                const int px = (int)(__fadd_rn(__fmul_rn(640.0f,     x),  0.001f));
                const int py = (int)(__fadd_rn(__fmul_rn(480.0f,     y),  0.001f));
                const int pt = (int)(__fadd_rn(__fmul_rn(1000000.0f, tt), 0.001f));
                vxy = px | (py << 16);
                vt  = pt;
            }
            sp_xy[idx] = vxy;
            sp_t[idx]  = vt;
        }
    }

    // ---- Pre-fill fin with -1 (merge overwrites matched slots, same every rep).
    reinterpret_cast<int4*>(&fin[0][0])[tid] = make_int4(-1, -1, -1, -1);
    __syncthreads();

    const int n = tid & (NPB - 1);
    const int q = tid >> 6;
    const int i = b0 + n;
    const int pxy = sp_xy[256 + n];
    const int ix = pxy & 0xffff;
    const int iy = pxy >> 16;
    const int it = sp_t[256 + n];
    const unsigned xyib = (unsigned)((ix + 8) | ((iy + 8) << 16));
    const int w0 = 255 + n - QW * q;
    const int* __restrict__ basep = &sp_xy[w0 - 63];
    const bool edgeb = (b0 & (NPG - 1)) < 256;
    unsigned char* myq = &qslot[n][q][0];

    #pragma unroll 1
    for (int rep = 0; rep < REPS; ++rep) {
        // ---- Scan: prefilter masks via packed 16-bit box test + vcc shift-insert.
        unsigned m0 = 0, m1 = 0;

        #pragma unroll 8
        for (int p = 0; p < 16; ++p) {
            const unsigned a = (unsigned)basep[63 - 2 * p];
            const unsigned b = (unsigned)basep[62 - 2 * p];
            unsigned t;
            asm("v_pk_sub_i16 %0, %2, %3\n\t"
                "v_and_b32 %0, 0xfff0fff0, %0\n\t"
                "v_cmp_eq_u32 vcc, 0, %0\n\t"
                "v_addc_co_u32 %1, vcc, %1, %1, vcc\n\t"
                "v_pk_sub_i16 %0, %2, %4\n\t"
                "v_and_b32 %0, 0xfff0fff0, %0\n\t"
                "v_cmp_eq_u32 vcc, 0, %0\n\t"
                "v_addc_co_u32 %1, vcc, %1, %1, vcc"
                : "=&v"(t), "+v"(m0)
                : "v"(xyib), "v"(a), "v"(b)
                : "vcc");
        }
        #pragma unroll 8
        for (int p = 16; p < 32; ++p) {
            const unsigned a = (unsigned)basep[63 - 2 * p];
            const unsigned b = (unsigned)basep[62 - 2 * p];
            unsigned t;
            asm("v_pk_sub_i16 %0, %2, %3\n\t"
                "v_and_b32 %0, 0xfff0fff0, %0\n\t"
                "v_cmp_eq_u32 vcc, 0, %0\n\t"
                "v_addc_co_u32 %1, vcc, %1, %1, vcc\n\t"
                "v_pk_sub_i16 %0, %2, %4\n\t"
                "v_and_b32 %0, 0xfff0fff0, %0\n\t"
                "v_cmp_eq_u32 vcc, 0, %0\n\t"
                "v_addc_co_u32 %1, vcc, %1, %1, vcc"
                : "=&v"(t), "+v"(m1)
                : "v"(xyib), "v"(a), "v"(b)
                : "vcc");
        }

        // ---- Post-pass: exact check on the rare prefilter hits.
        int cnt = 0;
        if (m0 | m1) {
            #pragma unroll
            for (int half = 0; half < 2; ++half) {
                unsigned m = half ? m1 : m0;
                const int sbase = half ? 32 : 0;
                while (m) {
                    const int lz = __clz(m);
                    m &= ~(0x80000000u >> lz);
                    const int s = sbase + lz;
                    const int idx = w0 - s;
                    const int pj = sp_xy[idx];
                    const int tj = sp_t[idx];
                    const int dx = ix - (pj & 0xffff);
                    const int dy = iy - (pj >> 16);
                    const int d2 = dx * dx + dy * dy;
                    const unsigned dt = (unsigned)(it - tj);
                    bool ok = (d2 <= RAD2) && (dt <= DTMAX);
                    if (edgeb) {
                        const int j = i - (QW * q + 1 + s);
                        ok = ok && (j >= 0) && ((j >> 15) == (i >> 15));
                    }
                    if (ok) {
                        if (cnt < MAXN) myq[cnt] = (unsigned char)(QW * q + s);
                        ++cnt;
                    }
                }
            }
        }
        scnt[n][q] = (unsigned char)(cnt < MAXN ? cnt : MAXN);
        __syncthreads();

        // ---- Merge quarter lists into fin[n] (global first-16 rule preserved).
        {
            const uchar4 c4 = *reinterpret_cast<const uchar4*>(&scnt[n][0]);
            const int c0 = c4.x, c1 = c4.y, c2 = c4.z, c3 = c4.w;
            int start = 0;
            if (q > 0) start += c0;
            if (q > 1) start += c1;
            if (q > 2) start += c2;
            const int cq = (q == 0) ? c0 : (q == 1) ? c1 : (q == 2) ? c2 : c3;
            for (int e = 0; e < cq; ++e) {
                const int k = start + e;
                if (k < MAXN) fin[n][k] = i - 1 - (int)myq[e];
            }
        }
        __syncthreads();
    }

    // ---- Stream fin -> global once: fully contiguous int4 bursts; dst derived.
    {
        const size_t base4 = (size_t)b0 * MAXN / 4;
        int4* __restrict__ gsrc = reinterpret_cast<int4*>(out) + base4;
        int4* __restrict__ gdst = reinterpret_cast<int4*>(out + (size_t)NTOT * MAXN) + base4;
        const int4 v = reinterpret_cast<const int4*>(&fin[0][0])[tid];
        const int row = b0 + (tid >> 2);
        int4 d;
        d.x = (v.x >= 0) ? row : -1;
        d.y = (v.y >= 0) ? row : -1;
        d.z = (v.z >= 0) ? row : -1;
        d.w = (v.w >= 0) ? row : -1;
        gsrc[tid] = v;
        gdst[tid] = d;
    }
}

extern "C" void kernel_launch(void* const* d_in, const int* in_sizes, int n_in,
                              void* d_out, int out_size, void* d_ws, size_t ws_size,
                              hipStream_t stream) {
    const float* pos = (const float*)d_in[0];
    int* out = (int*)d_out;
    tgn_edges_kernel<<<NTOT / NPB, 256, 0, stream>>>(pos, out);
}

// Round 7
// 24.130 us; speedup vs baseline: 3.5930x; 3.5930x over previous
//
#include <hip/hip_runtime.h>

// Problem constants (fixed by setup_inputs / reference)
#define NPG    32768          // nodes per batch group
#define NTOT   131072         // B * NPG
#define MAXN   16             // max neighbors kept
#define RAD2   49             // RADIUS_PX^2, RADIUS_PX = int(0.01*640+1) = 7
#define DTMAX  10000u         // int(0.01 * 1e6)
#define NPB    64             // nodes per block
#define NPW    16             // nodes per wave (4 waves/block)

// Structure: lane = offset. For each node, each of 4 subwindows (h) is tested
// by all 64 lanes at once; the hit set arrives as a wave-uniform 64-bit mask
// straight from __ballot (v_cmp -> sgpr pair). Hot path = 3 VALU + 1 ds_read
// per 64 pairs with NO serial vcc chain, no per-pass barriers, no merge.
__global__ __launch_bounds__(256, 8)
void tgn_edges_kernel(const float* __restrict__ pos, int* __restrict__ out) {
    __shared__ int sp_xy[320];     // packed (x | y<<16) for nodes [b0-256, b0+64)
    __shared__ int sp_t[320];      // t for same nodes
    __shared__ int sq_b[NPB];      // biased queries (x+8 | (y+8)<<16) for own nodes
    __shared__ int fin[NPB][MAXN]; // final src rows

    const int tid  = threadIdx.x;
    const int lane = tid & 63;
    const int wid  = tid >> 6;
    const int b0   = blockIdx.x * NPB;

    // ---- Stage + convert nodes [b0-256, b0+64) into LDS.
    #pragma unroll
    for (int s = 0; s < 2; ++s) {
        const int idx = s * 256 + tid;
        if (s == 0 || tid < NPB) {
            const int node = b0 - 256 + idx;
            int vxy = 0, vt = 0;
            if (node >= 0) {
                const float x  = pos[3 * node + 0];
                const float y  = pos[3 * node + 1];
                const float tt = pos[3 * node + 2];
                // Must bit-match numpy float32: int32(denorm*pos + 0.001).
                // __fmul_rn/__fadd_rn prevent FMA contraction.
                const int px = (int)(__fadd_rn(__fmul_rn(640.0f,     x),  0.001f));
                const int py = (int)(__fadd_rn(__fmul_rn(480.0f,     y),  0.001f));
                const int pt = (int)(__fadd_rn(__fmul_rn(1000000.0f, tt), 0.001f));
                vxy = px | (py << 16);   // both fit 16 bits
                vt  = pt;
            }
            sp_xy[idx] = vxy;
            sp_t[idx]  = vt;
            if (idx >= 256) sq_b[idx - 256] = vxy + 0x00080008;  // no cross-half carry
        }
    }
    // Pre-fill fin with -1 (LDS-only).
    reinterpret_cast<int4*>(&fin[0][0])[tid] = make_int4(-1, -1, -1, -1);
    __syncthreads();

    // ---- Scan: wave `wid` owns nodes [wn0, wn0+16). For node n, subwindow h,
    // lane l tests offset off = 64h + l + 1, i.e. sp index 256+wn0+n-64h-1-l.
    const int wn0 = wid * NPW;
    const bool edgeb = (b0 & (NPG - 1)) < 256;   // window may cross batch start
    // idx = (wn0 + 63 - lane) + (192 + n - 64h): base fixed per thread, rest is
    // a small element offset -> ds_read with immediate offsets after unroll.
    const int* __restrict__ baseN  = &sp_xy[wn0 + 63 - lane];
    const int* __restrict__ baseNt = &sp_t [wn0 + 63 - lane];

    #pragma unroll 2
    for (int n = 0; n < NPW; ++n) {
        const int i  = b0 + wn0 + n;
        const unsigned qb = (unsigned)sq_b[wn0 + n];   // broadcast read
        const int it = sp_t[256 + wn0 + n];            // broadcast read
        int cnt = 0;                                    // wave-uniform
        int* __restrict__ finrow = &fin[wn0 + n][0];

        #pragma unroll
        for (int h = 0; h < 4; ++h) {
            const int off0 = 192 + n - 64 * h;
            const unsigned nb = (unsigned)baseN[off0];
            unsigned d;   // packed (dx+8, dy+8) halves
            asm("v_pk_sub_i16 %0, %1, %2" : "=v"(d) : "v"(qb), "v"(nb));
            const unsigned tst = d & 0xfff0fff0u;       // 0 iff both halves in [0,15]
            unsigned long long m = __ballot(tst == 0);  // hit mask over offsets

            if (edgeb) {
                // Only offsets <= position-in-batch are same-batch & j>=0:
                // lane l valid iff l < avail.
                const int avail = (i & (NPG - 1)) - 64 * h;
                m = (avail >= 64) ? m
                  : ((avail <= 0) ? 0ull : (m & ((1ull << avail) - 1ull)));
            }

            if (m) {   // wave-uniform branch, ~5% of (node,subwindow)s
                const bool mybit = (m >> lane) & 1ull;
                const int  j = i - (64 * h + lane + 1);
                bool ok = false;
                if (mybit) {   // exec-masked exact check on rare hit lanes
                    const int tj = baseNt[off0];
                    const int dx = (int)(d & 0xffffu) - 8;   // exact: halves in [0,15]
                    const int dy = (int)(d >> 16)     - 8;
                    const int d2 = dx * dx + dy * dy;
                    const unsigned dt = (unsigned)(it - tj); // >=0: sorted, same batch
                    ok = (d2 <= RAD2) && (dt <= DTMAX);
                }
                const unsigned long long em = __ballot(ok);
                if (em) {
                    // Append in offset order: rank = #set bits below my lane.
                    const int rank = __popcll(em & ((1ull << lane) - 1ull));
                    const int k = cnt + rank;
                    if (ok && k < MAXN) finrow[k] = j;
                    cnt += __popcll(em);   // uncapped, matches reference rank
                }
            }
        }
    }
    __syncthreads();

    // ---- Stream fin -> global: fully contiguous int4 bursts; dst derived.
    {
        const size_t base4 = (size_t)b0 * MAXN / 4;
        int4* __restrict__ gsrc = reinterpret_cast<int4*>(out) + base4;
        int4* __restrict__ gdst = reinterpret_cast<int4*>(out + (size_t)NTOT * MAXN) + base4;
        const int4 v = reinterpret_cast<const int4*>(&fin[0][0])[tid];
        const int row = b0 + (tid >> 2);   // 4 consecutive int4s per output row
        int4 dd;
        dd.x = (v.x >= 0) ? row : -1;
        dd.y = (v.y >= 0) ? row : -1;
        dd.z = (v.z >= 0) ? row : -1;
        dd.w = (v.w >= 0) ? row : -1;
        gsrc[tid] = v;
        gdst[tid] = dd;
    }
}

extern "C" void kernel_launch(void* const* d_in, const int* in_sizes, int n_in,
                              void* d_out, int out_size, void* d_ws, size_t ws_size,
                              hipStream_t stream) {
    const float* pos = (const float*)d_in[0];
    int* out = (int*)d_out;
    tgn_edges_kernel<<<NTOT / NPB, 256, 0, stream>>>(pos, out);
}

// Round 8
// 16.527 us; speedup vs baseline: 5.2458x; 1.4600x over previous
//
#include <hip/hip_runtime.h>

// Problem constants (fixed by setup_inputs / reference)
#define NPG    32768          // nodes per batch group
#define NTOT   131072         // B * NPG
#define MAXN   16             // max neighbors kept
#define RAD2   49             // RADIUS_PX^2, RADIUS_PX = int(0.01*640+1) = 7
#define DTMAX  10000u         // int(0.01 * 1e6)
#define NPB    64             // nodes per block
#define NPW    16             // nodes per wave (4 waves/block)

// Diagonal-tile scan: wave owns 16 nodes. Lane l holds 5 register tiles of
// neighbors (j = wavebase-256+64t+l). Per (node,tile): query broadcast via
// v_readlane -> SGPR, then pk_sub + and + cmp(ballot) = 3 VALU per 64 pair
// tests. NO LDS and NO branch in the per-tile chain; one uniform branch per
// node on the OR of 5 ballots. Exact check + rank-append only on rare hits.
__global__ __launch_bounds__(256, 8)
void tgn_edges_kernel(const float* __restrict__ pos, int* __restrict__ out) {
    __shared__ int fin[NPB][MAXN];   // 4 KB; all accesses are wave-local

    const int tid      = threadIdx.x;
    const int lane     = tid & 63;
    const int wid      = tid >> 6;
    const int b0       = blockIdx.x * NPB;
    const int wn0      = wid * NPW;
    const int wavebase = b0 + wn0;

    // ---- Prefill fin with -1. Thread tid covers flat int4 slot tid = row
    // tid>>2, which lies in THIS wave's rows [wn0, wn0+16) -> no barrier.
    reinterpret_cast<int4*>(&fin[0][0])[tid] = make_int4(-1, -1, -1, -1);

    // ---- Load 5 neighbor tiles straight into registers (coalesced 12B/lane).
    int nbxy[5], nbt[5];
    #pragma unroll
    for (int t = 0; t < 5; ++t) {
        int node = wavebase - 256 + 64 * t + lane;
        node = node < 0 ? 0 : (node > NTOT - 1 ? NTOT - 1 : node);  // clamp; masked later
        const float x  = pos[3 * node + 0];
        const float y  = pos[3 * node + 1];
        const float tt = pos[3 * node + 2];
        // Must bit-match numpy float32: int32(denorm*pos + 0.001).
        // __fmul_rn/__fadd_rn prevent FMA contraction.
        const int px = (int)(__fadd_rn(__fmul_rn(640.0f,     x),  0.001f));
        const int py = (int)(__fadd_rn(__fmul_rn(480.0f,     y),  0.001f));
        const int pt = (int)(__fadd_rn(__fmul_rn(1000000.0f, tt), 0.001f));
        nbxy[t] = px | (py << 16);   // both fit 16 bits
        nbt[t]  = pt;
    }

    // ---- Uniform batch-boundary masks per tile: lane l valid iff j >= bstart.
    const int bstart = b0 & ~(NPG - 1);
    uint64_t smask[4];
    #pragma unroll
    for (int t = 0; t < 4; ++t) {
        const int sh = bstart - (wavebase - 256 + 64 * t);
        smask[t] = (sh <= 0) ? ~0ull : ((sh >= 64) ? 0ull : (~0ull << sh));
    }
    // t=4: jb == wavebase >= bstart always -> full.

    // Per-lane constant masks.
    const uint64_t mymask = 1ull << lane;
    const uint64_t gtmask = ~((mymask << 1) - 1ull);   // bits above lane (lane 63 -> 0)

    // ---- Scan: per node n, 5 ballots (register-only chain), 1 uniform branch.
    #pragma unroll 4
    for (int n = 0; n < NPW; ++n) {
        const int qxy = __builtin_amdgcn_readlane(nbxy[4], n);  // node wavebase+n
        const int qb  = qxy + 0x00080008;                       // biased query (SGPR)

        uint64_t bm[5];
        #pragma unroll
        for (int t = 0; t < 5; ++t) {
            unsigned d_;
            asm("v_pk_sub_i16 %0, %1, %2" : "=v"(d_) : "s"(qb), "v"(nbxy[t]));
            bm[t] = __ballot((d_ & 0xfff0fff0u) == 0u);  // both halves in [0,15]
        }

        const uint64_t cn  = (1ull << n) - 1ull;         // t4: lanes < n (excl. self)
        const uint64_t any = (bm[4] & cn) | bm[3] | bm[2] | bm[1] | bm[0];

        if (any) {   // wave-uniform, ~20% of nodes
            const int qt  = __builtin_amdgcn_readlane(nbt[4], n);
            int cnt = 0;

            // Process tiles in ascending-offset order: t = 4,3,2,1,0.
            // Within a tile, ascending offset == descending lane -> rank uses gtmask.
#define PROC_TILE(T, VALID)                                                          \
            do {                                                                     \
                const uint64_t hit = bm[T] & (VALID);                                \
                if (hit) {                                                           \
                    unsigned dd;                                                     \
                    asm("v_pk_sub_i16 %0, %1, %2"                                    \
                        : "=v"(dd) : "s"(qb), "v"(nbxy[T]));                         \
                    const int dx = (int)(dd & 0xffffu) - 8;  /* exact: in [0,15] */  \
                    const int dy = (int)(dd >> 16)     - 8;                          \
                    const int d2 = dx * dx + dy * dy;                                \
                    const unsigned dtv = (unsigned)(qt - nbt[T]);                    \
                    const bool okl = (d2 <= RAD2) && (dtv <= DTMAX);                 \
                    const uint64_t em = __ballot(okl) & hit;                         \
                    if (em) {                                                        \
                        const int rank = (int)__popcll(em & gtmask);                 \
                        const int k = cnt + rank;                                    \
                        const int j = wavebase - 256 + 64 * (T) + lane;              \
                        if ((em & mymask) && k < MAXN) fin[wn0 + n][k] = j;          \
                        cnt += (int)__popcll(em);                                    \
                    }                                                                \
                }                                                                    \
            } while (0)

            PROC_TILE(4, cn);
            PROC_TILE(3, smask[3]);
            PROC_TILE(2, smask[2]);
            PROC_TILE(1, smask[1]);
            PROC_TILE(0, ~cn & smask[0]);
#undef PROC_TILE
        }
    }

    // ---- Stream fin -> global (wave-local rows; no barrier needed).
    {
        const size_t base4 = (size_t)b0 * MAXN / 4;
        int4* __restrict__ gsrc = reinterpret_cast<int4*>(out) + base4;
        int4* __restrict__ gdst = reinterpret_cast<int4*>(out + (size_t)NTOT * MAXN) + base4;
        const int4 v = reinterpret_cast<const int4*>(&fin[0][0])[tid];
        const int row = b0 + (tid >> 2);   // 4 consecutive int4s per output row
        int4 dd;
        dd.x = (v.x >= 0) ? row : -1;
        dd.y = (v.y >= 0) ? row : -1;
        dd.z = (v.z >= 0) ? row : -1;
        dd.w = (v.w >= 0) ? row : -1;
        gsrc[tid] = v;
        gdst[tid] = dd;
    }
}

extern "C" void kernel_launch(void* const* d_in, const int* in_sizes, int n_in,
                              void* d_out, int out_size, void* d_ws, size_t ws_size,
                              hipStream_t stream) {
    const float* pos = (const float*)d_in[0];
    int* out = (int*)d_out;
    tgn_edges_kernel<<<NTOT / NPB, 256, 0, stream>>>(pos, out);
}

// Round 9
// 15.122 us; speedup vs baseline: 5.7332x; 1.0929x over previous
//
#include <hip/hip_runtime.h>

// Problem constants (fixed by setup_inputs / reference)
#define NPG    32768          // nodes per batch group
#define NTOT   131072         // B * NPG
#define MAXN   16             // max neighbors kept
#define RAD2   49             // RADIUS_PX^2, RADIUS_PX = int(0.01*640+1) = 7
#define DTMAX  10000u         // int(0.01 * 1e6)
#define NPB    64             // nodes per block
#define QW     64             // offsets per quarter-window (256 = 4 x 64)

// Round-5 structure (thread = node-quarter, branchless LDS+VALU stream) with
// group-of-8 min-accumulation: per pair pk_sub+and+min (3 VALU, no vcc chain),
// one cmp+addc per 8 pairs -> 3.13 VALU/pair vs 4. Post-pass rescans only hit
// groups (rare), then the proven qslot/merge/coalesced-streamout epilogue.
__global__ __launch_bounds__(256, 8)
void tgn_edges_kernel(const float* __restrict__ pos, int* __restrict__ out) {
    __shared__ int           sp_xy[320];             // packed (x | y<<16) for nodes [b0-256, b0+64)
    __shared__ int           sp_t[320];              // t for same nodes
    __shared__ unsigned char qslot[NPB][4][MAXN];    // per-(node,quarter) matches: stores off-1
    __shared__ unsigned char scnt[NPB][4];           // per-(node,quarter) match count (capped 16)
    __shared__ int           fin[NPB][MAXN];         // final src rows for this block

    const int tid = threadIdx.x;
    const int b0  = blockIdx.x * NPB;

    // ---- Stage + convert nodes [b0-256, b0+64) into LDS (320 nodes, 256 threads).
    #pragma unroll
    for (int s = 0; s < 2; ++s) {
        const int idx = s * 256 + tid;
        if (s == 0 || tid < NPB) {
            const int node = b0 - 256 + idx;
            int vxy = 0, vt = 0;
            if (node >= 0) {
                const float x  = pos[3 * node + 0];
                const float y  = pos[3 * node + 1];
                const float tt = pos[3 * node + 2];
                // Must bit-match numpy float32: int32(denorm*pos + 0.001).
                // __fmul_rn/__fadd_rn prevent FMA contraction.
                const int px = (int)(__fadd_rn(__fmul_rn(640.0f,     x),  0.001f));
                const int py = (int)(__fadd_rn(__fmul_rn(480.0f,     y),  0.001f));
                const int pt = (int)(__fadd_rn(__fmul_rn(1000000.0f, tt), 0.001f));
                vxy = px | (py << 16);   // both fit 16 bits
                vt  = pt;
            }
            sp_xy[idx] = vxy;
            sp_t[idx]  = vt;
        }
    }

    // ---- Pre-fill fin with -1 (LDS-only; merge overwrites matched slots).
    reinterpret_cast<int4*>(&fin[0][0])[tid] = make_int4(-1, -1, -1, -1);
    __syncthreads();

    // ---- Scan: thread (n, q) scans offsets [QW*q+1, QW*q+QW] for node i = b0+n.
    const int n = tid & (NPB - 1);
    const int q = tid >> 6;
    const int i = b0 + n;
    const int pxy = sp_xy[256 + n];
    const int ix = pxy & 0xffff;
    const int iy = pxy >> 16;
    const int it = sp_t[256 + n];
    // Biased query: halves are (ix+8, iy+8). Prefilter: dx+8, dy+8 both in [0,15].
    const unsigned qb = (unsigned)(pxy + 0x00080008);   // no cross-half carry
    const int w0 = 255 + n - QW * q;     // sp index for off = QW*q+1 (s=0); idx = w0 - s
    const int* __restrict__ basep = &sp_xy[w0 - 63];    // basep[63 - s] = sp_xy[w0 - s]

    // ---- 8 groups of 8 offsets; gm bit (7-g) set iff group g has a box hit.
    unsigned gm = 0;
    #pragma unroll
    for (int g = 0; g < 8; ++g) {
        const int base = 63 - 8 * g;     // basep index for k = 0 (s = 8g)
        unsigned acc = 0xffffffffu;
        #pragma unroll
        for (int k = 0; k < 8; ++k) {
            const unsigned nb = (unsigned)basep[base - k];
            unsigned d_;
            asm("v_pk_sub_i16 %0, %1, %2" : "=v"(d_) : "v"(qb), "v"(nb));
            const unsigned tst = d_ & 0xfff0fff0u;   // 0 iff both halves in [0,15]
            acc = (k == 0) ? tst : (acc < tst ? acc : tst);   // v_min_u32
        }
        // gm = 2*gm + (acc == 0)   (single cmp+addc per 8 pairs)
        asm("v_cmp_eq_u32 vcc, 0, %1\n\t"
            "v_addc_co_u32 %0, vcc, %0, %0, vcc"
            : "+v"(gm) : "v"(acc) : "vcc");
    }

    // ---- Post-pass: exact re-scan of the rare hit groups (ascending g).
    // Edge blocks (window may cross batch boundary / j<0): b0 mod 32768 < 256.
    const bool edgeb = (b0 & (NPG - 1)) < 256;
    int cnt = 0;
    unsigned char* myq = &qslot[n][q][0];
    while (gm) {
        const int lz = __clz(gm);            // gm bits live in [0,7] -> lz in [24,31]
        const int g  = lz - 24;              // highest bit = smallest g = ascending order
        gm &= ~(0x80000000u >> lz);
        #pragma unroll
        for (int k = 0; k < 8; ++k) {
            const int s   = 8 * g + k;
            const int idx = w0 - s;
            const int pj  = sp_xy[idx];
            const int tj  = sp_t[idx];
            const int dx  = ix - (pj & 0xffff);
            const int dy  = iy - (pj >> 16);
            const int d2  = dx * dx + dy * dy;
            const unsigned dt = (unsigned)(it - tj);   // >=0: sorted, same batch
            bool ok = (d2 <= RAD2) && (dt <= DTMAX);
            if (edgeb) {
                const int j = i - (QW * q + 1 + s);
                ok = ok && (j >= 0) && ((j >> 15) == (i >> 15));
            }
            if (ok) {
                if (cnt < MAXN) myq[cnt] = (unsigned char)(QW * q + s);   // off-1
                ++cnt;
            }
        }
    }
    scnt[n][q] = (unsigned char)(cnt < MAXN ? cnt : MAXN);
    __syncthreads();

    // ---- Merge: thread (n,q) copies its quarter's matches into fin[n] at the
    // prefix offset over lower quarters (global first-16 rule preserved:
    // per-quarter counts are capped at 16, so later quarters start >=16 and drop).
    {
        const uchar4 c4 = *reinterpret_cast<const uchar4*>(&scnt[n][0]);
        const int c0 = c4.x, c1 = c4.y, c2 = c4.z, c3 = c4.w;
        int start = 0;
        if (q > 0) start += c0;
        if (q > 1) start += c1;
        if (q > 2) start += c2;
        const int cq = (q == 0) ? c0 : (q == 1) ? c1 : (q == 2) ? c2 : c3;
        for (int e = 0; e < cq; ++e) {
            const int k = start + e;
            if (k < MAXN) fin[n][k] = i - 1 - (int)myq[e];   // j = i - off
        }
    }
    __syncthreads();

    // ---- Stream fin -> global: fully contiguous int4 bursts; dst derived.
    {
        const size_t base4 = (size_t)b0 * MAXN / 4;
        int4* __restrict__ gsrc = reinterpret_cast<int4*>(out) + base4;
        int4* __restrict__ gdst = reinterpret_cast<int4*>(out + (size_t)NTOT * MAXN) + base4;
        const int4 v = reinterpret_cast<const int4*>(&fin[0][0])[tid];
        const int row = b0 + (tid >> 2);   // 4 consecutive int4s per output row
        int4 d;
        d.x = (v.x >= 0) ? row : -1;
        d.y = (v.y >= 0) ? row : -1;
        d.z = (v.z >= 0) ? row : -1;
        d.w = (v.w >= 0) ? row : -1;
        gsrc[tid] = v;
        gdst[tid] = d;
    }
}

extern "C" void kernel_launch(void* const* d_in, const int* in_sizes, int n_in,
                              void* d_out, int out_size, void* d_ws, size_t ws_size,
                              hipStream_t stream) {
    const float* pos = (const float*)d_in[0];
    int* out = (int*)d_out;
    tgn_edges_kernel<<<NTOT / NPB, 256, 0, stream>>>(pos, out);
}

// Round 10
// 14.074 us; speedup vs baseline: 6.1604x; 1.0745x over previous
//
#include <hip/hip_runtime.h>

// Problem constants (fixed by setup_inputs / reference)
#define NPG    32768          // nodes per batch group
#define NTOT   131072         // B * NPG
#define MAXN   16             // max neighbors kept
#define RAD2   49             // RADIUS_PX^2, RADIUS_PX = int(0.01*640+1) = 7
#define DTMAX  10000u         // int(0.01 * 1e6)
#define NPB    64             // nodes per block
#define QW     64             // offsets per quarter-window (256 = 4 x 64)

// Round-5 structure (thread = node-quarter, branchless LDS+VALU stream, exact
// per-offset masks) with the two 32-bit mask chains interleaved on INDEPENDENT
// carry registers (m0 -> vcc, m1 -> explicit SGPR pair, VOP3 forms) to remove
// the single-vcc serialization that capped VALUBusy at ~75%.
__global__ __launch_bounds__(256, 8)
void tgn_edges_kernel(const float* __restrict__ pos, int* __restrict__ out) {
    __shared__ int           sp_xy[320];             // packed (x | y<<16) for nodes [b0-256, b0+64)
    __shared__ int           sp_t[320];              // t for same nodes
    __shared__ unsigned char qslot[NPB][4][MAXN];    // per-(node,quarter) matches: stores off-1
    __shared__ unsigned char scnt[NPB][4];           // per-(node,quarter) match count (capped 16)
    __shared__ int           fin[NPB][MAXN];         // final src rows for this block

    const int tid = threadIdx.x;
    const int b0  = blockIdx.x * NPB;

    // ---- Stage + convert nodes [b0-256, b0+64) into LDS (320 nodes, 256 threads).
    #pragma unroll
    for (int s = 0; s < 2; ++s) {
        const int idx = s * 256 + tid;
        if (s == 0 || tid < NPB) {
            const int node = b0 - 256 + idx;
            int vxy = 0, vt = 0;
            if (node >= 0) {
                const float x  = pos[3 * node + 0];
                const float y  = pos[3 * node + 1];
                const float tt = pos[3 * node + 2];
                // Must bit-match numpy float32: int32(denorm*pos + 0.001).
                // __fmul_rn/__fadd_rn prevent FMA contraction.
                const int px = (int)(__fadd_rn(__fmul_rn(640.0f,     x),  0.001f));
                const int py = (int)(__fadd_rn(__fmul_rn(480.0f,     y),  0.001f));
                const int pt = (int)(__fadd_rn(__fmul_rn(1000000.0f, tt), 0.001f));
                vxy = px | (py << 16);   // both fit 16 bits
                vt  = pt;
            }
            sp_xy[idx] = vxy;
            sp_t[idx]  = vt;
        }
    }

    // ---- Pre-fill fin with -1 (LDS-only; merge overwrites matched slots).
    reinterpret_cast<int4*>(&fin[0][0])[tid] = make_int4(-1, -1, -1, -1);
    __syncthreads();

    // ---- Scan: thread (n, q) scans offsets [QW*q+1, QW*q+QW] for node i = b0+n.
    const int n = tid & (NPB - 1);
    const int q = tid >> 6;
    const int i = b0 + n;
    const int pxy = sp_xy[256 + n];
    const int ix = pxy & 0xffff;
    const int iy = pxy >> 16;
    const int it = sp_t[256 + n];
    // Biased query: halves are (ix+8, iy+8). Prefilter: dx+8, dy+8 both in [0,15].
    const unsigned qb = (unsigned)(pxy + 0x00080008);   // no cross-half carry
    const int w0 = 255 + n - QW * q;     // sp index for off = QW*q+1 (s=0); idx = w0 - s
    const int* __restrict__ basep = &sp_xy[w0 - 63];    // basep[63 - s] = sp_xy[w0 - s]

    // ---- Exact prefilter masks. m0 holds s=0..31 (s=0 at bit 31), m1 s=32..63.
    // Two independent shift-insert chains: m0 via vcc, m1 via an SGPR pair
    // (VOP3 cmp/addc) -> no shared-carry serialization.
    unsigned m0 = 0, m1 = 0;
    unsigned long long c1;
    #pragma unroll
    for (int p = 0; p < 32; ++p) {
        const unsigned a = (unsigned)basep[63 - p];   // s = p      -> m0
        const unsigned b = (unsigned)basep[31 - p];   // s = 32+p   -> m1
        unsigned ta, tb;
        asm("v_pk_sub_i16 %0, %5, %6\n\t"
            "v_pk_sub_i16 %1, %5, %7\n\t"
            "v_and_b32 %0, 0xfff0fff0, %0\n\t"
            "v_and_b32 %1, 0xfff0fff0, %1\n\t"
            "v_cmp_eq_u32 vcc, 0, %0\n\t"
            "v_cmp_eq_u32 %4, 0, %1\n\t"
            "v_addc_co_u32 %2, vcc, %2, %2, vcc\n\t"
            "v_addc_co_u32 %3, %4, %3, %3, %4"
            : "=&v"(ta), "=&v"(tb), "+v"(m0), "+v"(m1), "=&s"(c1)
            : "v"(qb), "v"(a), "v"(b)
            : "vcc");
    }

    // ---- Post-pass: exact check on the rare prefilter hits.
    // Edge blocks (window may cross batch boundary / j<0): b0 mod 32768 < 256.
    const bool edgeb = (b0 & (NPG - 1)) < 256;
    int cnt = 0;
    unsigned char* myq = &qslot[n][q][0];
    if (m0 | m1) {
        #pragma unroll
        for (int half = 0; half < 2; ++half) {
            unsigned m = half ? m1 : m0;
            const int sbase = half ? 32 : 0;
            while (m) {
                const int lz = __clz(m);
                m &= ~(0x80000000u >> lz);
                const int s = sbase + lz;
                const int idx = w0 - s;
                const int pj = sp_xy[idx];
                const int tj = sp_t[idx];
                const int dx = ix - (pj & 0xffff);
                const int dy = iy - (pj >> 16);
                const int d2 = dx * dx + dy * dy;
                const unsigned dt = (unsigned)(it - tj);  // dt>=0 auto (sorted, same batch)
                bool ok = (d2 <= RAD2) && (dt <= DTMAX);
                if (edgeb) {
                    const int j = i - (QW * q + 1 + s);
                    ok = ok && (j >= 0) && ((j >> 15) == (i >> 15));
                }
                if (ok) {
                    if (cnt < MAXN) myq[cnt] = (unsigned char)(QW * q + s);  // off-1
                    ++cnt;
                }
            }
        }
    }
    scnt[n][q] = (unsigned char)(cnt < MAXN ? cnt : MAXN);
    __syncthreads();

    // ---- Merge: thread (n,q) copies its quarter's matches into fin[n] at the
    // prefix offset over lower quarters (global first-16 rule preserved:
    // per-quarter counts are capped at 16, so later quarters start >=16 and drop).
    {
        const uchar4 c4 = *reinterpret_cast<const uchar4*>(&scnt[n][0]);
        const int c0 = c4.x, c1_ = c4.y, c2 = c4.z, c3 = c4.w;
        int start = 0;
        if (q > 0) start += c0;
        if (q > 1) start += c1_;
        if (q > 2) start += c2;
        const int cq = (q == 0) ? c0 : (q == 1) ? c1_ : (q == 2) ? c2 : c3;
        for (int e = 0; e < cq; ++e) {
            const int k = start + e;
            if (k < MAXN) fin[n][k] = i - 1 - (int)myq[e];   // j = i - off
        }
    }
    __syncthreads();

    // ---- Stream fin -> global: fully contiguous int4 bursts; dst derived.
    {
        const size_t base4 = (size_t)b0 * MAXN / 4;
        int4* __restrict__ gsrc = reinterpret_cast<int4*>(out) + base4;
        int4* __restrict__ gdst = reinterpret_cast<int4*>(out + (size_t)NTOT * MAXN) + base4;
        const int4 v = reinterpret_cast<const int4*>(&fin[0][0])[tid];
        const int row = b0 + (tid >> 2);   // 4 consecutive int4s per output row
        int4 d;
        d.x = (v.x >= 0) ? row : -1;
        d.y = (v.y >= 0) ? row : -1;
        d.z = (v.z >= 0) ? row : -1;
        d.w = (v.w >= 0) ? row : -1;
        gsrc[tid] = v;
        gdst[tid] = d;
    }
}

extern "C" void kernel_launch(void* const* d_in, const int* in_sizes, int n_in,
                              void* d_out, int out_size, void* d_ws, size_t ws_size,
                              hipStream_t stream) {
    const float* pos = (const float*)d_in[0];
    int* out = (int*)d_out;
    tgn_edges_kernel<<<NTOT / NPB, 256, 0, stream>>>(pos, out);
}

// Round 11
// 13.429 us; speedup vs baseline: 6.4562x; 1.0480x over previous
//
#include <hip/hip_runtime.h>

// Problem constants (fixed by setup_inputs / reference)
#define NPG    32768          // nodes per batch group
#define NTOT   131072         // B * NPG
#define MAXN   16             // max neighbors kept
#define RAD2   49             // RADIUS_PX^2, RADIUS_PX = int(0.01*640+1) = 7
#define DTMAX  10000u         // int(0.01 * 1e6)
#define NPB    64             // nodes per block
#define GX     20             // x cells (32 px each, x in [0,639])
#define GY     16             // y cells (30 px each, y in [0,479])
#define NCELL  (GX*GY)        // 320
#define SLOTS  16             // slots per cell (lambda ~= 1.0 -> overflow ~1e-15)

// Hash-grid scan: instead of 256 pair-tests per node, bucket the 320-node
// window into 32x30px cells (match needs |dx|<=7,|dy|<=7 -> 2x2 cells).
// Thread = (node, cell-quadrant). First 4 slots checked branchlessly from a
// ds_read_b128 prefetch (no per-candidate branch / latency chain); matches
// merged by the quadrant-0 lane via insertion sort by j descending (== the
// reference first-16-by-rank rule; deterministic regardless of atomic order).
__global__ __launch_bounds__(256, 5)
void tgn_edges_kernel(const float* __restrict__ pos, int* __restrict__ out) {
    __shared__ int2 sp[320];              // (x|y<<16, t) for window idx (node = b0-256+idx)
    __shared__ int  cellcnt[NCELL];       // per-cell insert count
    __shared__ int  cells[NCELL][SLOTS];  // per-cell window-idx lists (-1 = empty)
    __shared__ int  fin[NPB][MAXN];       // final src rows, sorted by j descending

    const int tid = threadIdx.x;
    const int b0  = blockIdx.x * NPB;

    // ---- Phase 0: init LDS (cells = -1 sentinel, counts = 0, fin = -1).
    {
        const int4 m1 = make_int4(-1, -1, -1, -1);
        int4* c4 = reinterpret_cast<int4*>(&cells[0][0]);   // 1280 int4
        #pragma unroll
        for (int k = 0; k < 5; ++k) c4[k * 256 + tid] = m1;
        cellcnt[tid] = 0;
        if (tid < NCELL - 256) cellcnt[256 + tid] = 0;
        reinterpret_cast<int4*>(&fin[0][0])[tid] = m1;      // 256 int4
    }
    __syncthreads();

    // ---- Phase 1: stage + convert + insert nodes [b0-256, b0+64).
    #pragma unroll
    for (int s = 0; s < 2; ++s) {
        const int idx = s * 256 + tid;
        if (s == 0 || tid < 320 - 256) {
            const int node = b0 - 256 + idx;
            if (node >= 0) {
                const float x  = pos[3 * node + 0];
                const float y  = pos[3 * node + 1];
                const float tt = pos[3 * node + 2];
                // Must bit-match numpy float32: int32(denorm*pos + 0.001).
                // __fmul_rn/__fadd_rn prevent FMA contraction.
                const int px = (int)(__fadd_rn(__fmul_rn(640.0f,     x),  0.001f));
                const int py = (int)(__fadd_rn(__fmul_rn(480.0f,     y),  0.001f));
                const int pt = (int)(__fadd_rn(__fmul_rn(1000000.0f, tt), 0.001f));
                sp[idx] = make_int2(px | (py << 16), pt);
                // cell = (py/30)*GX + px/32   (magic /30: y*2185>>16, exact for y<=646)
                const int cell = ((py * 2185) >> 16) * GX + (px >> 5);
                const int slot = atomicAdd(&cellcnt[cell], 1);
                if (slot < SLOTS) cells[cell][slot] = idx;
            }
        }
    }
    __syncthreads();

    // ---- Phase 2: query. Thread = (node n, quadrant qq).
    const int n    = tid >> 2;
    const int qq   = tid & 3;
    const int lane = tid & 63;
    const int2 pown = sp[256 + n];
    const int x  = pown.x & 0xffff;
    const int y  = pown.x >> 16;
    const int it = pown.y;

    const int xlo = x > 7 ? x - 7 : 0;
    const int xhi = x < 632 ? x + 7 : 639;
    const int ylo = y > 7 ? y - 7 : 0;
    const int yhi = y < 472 ? y + 7 : 479;
    const int cx0 = xlo >> 5,              cx1 = xhi >> 5;
    const int cy0 = (ylo * 2185) >> 16,    cy1 = (yhi * 2185) >> 16;
    const int cx  = (qq & 1) ? cx1 : cx0;
    const int cy  = (qq & 2) ? cy1 : cy0;
    const bool dup = (((qq & 1) != 0) & (cx1 == cx0)) | (((qq & 2) != 0) & (cy1 == cy0));
    const int cell = cy * GX + cx;
    int c = dup ? 0 : cellcnt[cell];
    c = c > SLOTS ? SLOTS : c;

    // Window/batch bounds on candidate idx: j = b0-256+idx valid iff
    // idx in [max(n, 256-boff), n+255]  (covers j>=0, same batch, j<i).
    const int boff   = b0 & (NPG - 1);
    const int idxmin = (256 - boff) > n ? (256 - boff) : n;
    const int idxmax = n + 255;

    unsigned bm = 0;   // bit k set iff slot k of my cell is a true match
    if (c > 0) {
        const int4 s4 = *reinterpret_cast<const int4*>(&cells[cell][0]);
        const int sl[4] = {s4.x, s4.y, s4.z, s4.w};
        #pragma unroll
        for (int k = 0; k < 4; ++k) {   // branchless first 4 slots
            const int idx = sl[k];
            bool ok = (k < c) & (idx >= idxmin) & (idx <= idxmax);
            const int ii = ok ? idx : 0;          // clamp LDS addr (value unused if !ok)
            const int2 pj = sp[ii];
            const int dx = x - (pj.x & 0xffff);
            const int dy = y - (pj.x >> 16);
            const unsigned dt = (unsigned)(it - pj.y);   // >=0: sorted, same batch
            ok = ok & (dx * dx + dy * dy <= RAD2) & (dt <= DTMAX);
            bm |= ok ? (1u << k) : 0u;
        }
        if (c > 4) {   // rare tail (P(cell count > 4) ~ 0.4%)
            for (int k = 4; k < c; ++k) {
                const int idx = cells[cell][k];
                bool ok = (idx >= idxmin) & (idx <= idxmax);
                const int ii = ok ? idx : 0;
                const int2 pj = sp[ii];
                const int dx = x - (pj.x & 0xffff);
                const int dy = y - (pj.x >> 16);
                const unsigned dt = (unsigned)(it - pj.y);
                ok = ok & (dx * dx + dy * dy <= RAD2) & (dt <= DTMAX);
                bm |= ok ? (1u << k) : 0u;
            }
        }
    }

    // ---- Merge: quadrant-0 lane gathers the 4 bitmasks + cells and
    // insertion-sorts matches into fin[n] by j DESCENDING (= ascending off,
    // the reference rank order), keeping the 16 largest j.
    const int gb = lane & ~3;
    unsigned bmq[4];
    int      clq[4];
    #pragma unroll
    for (int q2 = 0; q2 < 4; ++q2) {
        bmq[q2] = __shfl(bm,   gb + q2);
        clq[q2] = __shfl(cell, gb + q2);
    }
    if (qq == 0 && (bmq[0] | bmq[1] | bmq[2] | bmq[3])) {
        int m = 0;
        #pragma unroll
        for (int q2 = 0; q2 < 4; ++q2) {
            unsigned mm = bmq[q2];
            const int cl = clq[q2];
            while (mm) {
                const int k = __ffs(mm) - 1;
                mm &= mm - 1;
                const int j = b0 - 256 + cells[cl][k];
                // insertion into fin[n] (desc by j); fin prefilled -1 < any j
                int p = m < MAXN ? m : MAXN;
                while (p > 0 && fin[n][p - 1] < j) {
                    if (p < MAXN) fin[n][p] = fin[n][p - 1];
                    --p;
                }
                if (p < MAXN) fin[n][p] = j;
                ++m;
            }
        }
    }
    __syncthreads();

    // ---- Stream fin -> global: fully contiguous int4 bursts; dst derived.
    {
        const size_t base4 = (size_t)b0 * MAXN / 4;
        int4* __restrict__ gsrc = reinterpret_cast<int4*>(out) + base4;
        int4* __restrict__ gdst = reinterpret_cast<int4*>(out + (size_t)NTOT * MAXN) + base4;
        const int4 v = reinterpret_cast<const int4*>(&fin[0][0])[tid];
        const int row = b0 + (tid >> 2);   // 4 consecutive int4s per output row
        int4 d;
        d.x = (v.x >= 0) ? row : -1;
        d.y = (v.y >= 0) ? row : -1;
        d.z = (v.z >= 0) ? row : -1;
        d.w = (v.w >= 0) ? row : -1;
        gsrc[tid] = v;
        gdst[tid] = d;
    }
}

extern "C" void kernel_launch(void* const* d_in, const int* in_sizes, int n_in,
                              void* d_out, int out_size, void* d_ws, size_t ws_size,
                              hipStream_t stream) {
    const float* pos = (const float*)d_in[0];
    int* out = (int*)d_out;
    tgn_edges_kernel<<<NTOT / NPB, 256, 0, stream>>>(pos, out);
}

// Round 12
// 13.090 us; speedup vs baseline: 6.6233x; 1.0259x over previous
//
#include <hip/hip_runtime.h>

// Problem constants (fixed by setup_inputs / reference)
#define NPG    32768          // nodes per batch group
#define NTOT   131072         // B * NPG
#define MAXN   16             // max neighbors kept
#define RAD2   49             // RADIUS_PX^2, RADIUS_PX = int(0.01*640+1) = 7
#define DTMAX  10000u         // int(0.01 * 1e6)
#define NPB    256            // nodes (queries) per block
#define WINSZ  512            // staged window entries: [b0-256, b0+256)
#define GX     20             // x cells (32 px each, x in [0,639])
#define GY     16             // y cells (30 px each, y in [0,479])
#define NCELL  (GX*GY)        // 320
#define SLOTS  16             // slots per cell (lambda ~= 1.6 -> overflow ~1e-10)

// Hash-grid, amortized: one 512-node grid serves 256 queries (4x round 11).
// Thread = node. Each thread walks its <=2x2 cell neighborhood (avg 2.1
// cells, ~6 candidates), probing 4 slots branchlessly per cell from one
// ds_read_b128; owns its fin row -> no shfl merge; insertion sort by j
// descending (== reference first-16-by-rank) only on rare hits.
__global__ __launch_bounds__(256, 2)
void tgn_edges_kernel(const float* __restrict__ pos, int* __restrict__ out) {
    __shared__ int2 sp[WINSZ];            // (x|y<<16, t); window idx -> node = b0-256+idx
    __shared__ int  cellcnt[NCELL];       // per-cell insert count
    __shared__ int  cells[NCELL][SLOTS];  // per-cell window-idx lists (slots >= cnt untrusted)
    __shared__ int  fin[NPB][MAXN];       // final src rows, sorted by j descending

    const int tid = threadIdx.x;
    const int b0  = blockIdx.x * NPB;

    // ---- Phase 0: init (cell counts zero, fin -1; cells array needs NO init).
    cellcnt[tid] = 0;
    if (tid < NCELL - 256) cellcnt[256 + tid] = 0;
    {
        const int4 m1 = make_int4(-1, -1, -1, -1);
        int4* f4 = reinterpret_cast<int4*>(&fin[0][0]);    // 1024 int4
        #pragma unroll
        for (int k = 0; k < 4; ++k) f4[k * 256 + tid] = m1;
    }
    __syncthreads();

    // ---- Phase 1: stage + convert + insert nodes [b0-256, b0+256).
    #pragma unroll
    for (int s = 0; s < 2; ++s) {
        const int idx  = s * 256 + tid;
        const int node = b0 - 256 + idx;
        int2 v = make_int2(0, 0);
        if (node >= 0) {
            const float x  = pos[3 * node + 0];
            const float y  = pos[3 * node + 1];
            const float tt = pos[3 * node + 2];
            // Must bit-match numpy float32: int32(denorm*pos + 0.001).
            // __fmul_rn/__fadd_rn prevent FMA contraction.
            const int px = (int)(__fadd_rn(__fmul_rn(640.0f,     x),  0.001f));
            const int py = (int)(__fadd_rn(__fmul_rn(480.0f,     y),  0.001f));
            const int pt = (int)(__fadd_rn(__fmul_rn(1000000.0f, tt), 0.001f));
            v = make_int2(px | (py << 16), pt);
            // cell = (py/30)*GX + px/32   (magic /30: y*2185>>16, exact for y<=646)
            if (idx != WINSZ - 1) {   // last entry can never be a candidate (j < i)
                const int cell = ((py * 2185) >> 16) * GX + (px >> 5);
                const int slot = atomicAdd(&cellcnt[cell], 1);
                if (slot < SLOTS) cells[cell][slot] = idx;
            }
        }
        sp[idx] = v;
    }
    __syncthreads();

    // ---- Phase 2: query. Thread = node n; i = b0 + n (window idx 256+n).
    const int n  = tid;
    const int2 pown = sp[256 + n];
    const int x  = pown.x & 0xffff;
    const int y  = pown.x >> 16;
    const int it = pown.y;

    const int xlo = x > 7 ? x - 7 : 0;
    const int xhi = x < 632 ? x + 7 : 639;
    const int ylo = y > 7 ? y - 7 : 0;
    const int yhi = y < 472 ? y + 7 : 479;
    const int cx0 = xlo >> 5,           cx1 = xhi >> 5;
    const int cy0 = (ylo * 2185) >> 16, cy1 = (yhi * 2185) >> 16;

    // Valid candidate window-idx range: j = b0-256+idx with j in same batch,
    // j >= 0, and i-256 <= j <= i-1  ->  idx in [max(n, 256-boff), n+255].
    const int boff   = b0 & (NPG - 1);
    const int idxmin = (256 - boff) > n ? (256 - boff) : n;
    const int idxmax = n + 255;

    int m = 0;   // matches found so far (uncapped rank)
    for (int cy = cy0; cy <= cy1; ++cy) {
        for (int cx = cx0; cx <= cx1; ++cx) {
            const int cell = cy * GX + cx;
            int c = cellcnt[cell];
            c = c > SLOTS ? SLOTS : c;
            unsigned bm = 0;   // bit k: slot k is a true match
            if (c > 0) {
                const int4 s4 = *reinterpret_cast<const int4*>(&cells[cell][0]);
                const int sl[4] = {s4.x, s4.y, s4.z, s4.w};
                #pragma unroll
                for (int k = 0; k < 4; ++k) {   // branchless first 4 slots
                    const int idx = sl[k];
                    bool ok = (k < c) & (idx >= idxmin) & (idx <= idxmax);
                    const int ii = ok ? idx : 0;     // safe LDS addr; dead if !ok
                    const int2 pj = sp[ii];
                    const int dx = x - (pj.x & 0xffff);
                    const int dy = y - (pj.x >> 16);
                    const unsigned dt = (unsigned)(it - pj.y);  // >=0: sorted, same batch
                    ok = ok & (dx * dx + dy * dy <= RAD2) & (dt <= DTMAX);
                    bm |= ok ? (1u << k) : 0u;
                }
                if (c > 4) {   // rare tail
                    for (int k = 4; k < c; ++k) {
                        const int idx = cells[cell][k];
                        bool ok = (idx >= idxmin) & (idx <= idxmax);
                        const int ii = ok ? idx : 0;
                        const int2 pj = sp[ii];
                        const int dx = x - (pj.x & 0xffff);
                        const int dy = y - (pj.x >> 16);
                        const unsigned dt = (unsigned)(it - pj.y);
                        ok = ok & (dx * dx + dy * dy <= RAD2) & (dt <= DTMAX);
                        bm |= ok ? (1u << k) : 0u;
                    }
                }
            }
            // Rare: insert matches into fin[n], sorted by j DESC (= rank order),
            // keeping the 16 largest j. Deterministic vs atomic insert order.
            while (bm) {
                const int k = __ffs(bm) - 1;
                bm &= bm - 1;
                const int j = b0 - 256 + cells[cell][k];
                int p = m < MAXN ? m : MAXN;
                while (p > 0 && fin[n][p - 1] < j) {
                    if (p < MAXN) fin[n][p] = fin[n][p - 1];
                    --p;
                }
                if (p < MAXN) fin[n][p] = j;
                ++m;
            }
        }
    }
    __syncthreads();

    // ---- Stream fin -> global: fully contiguous int4 bursts; dst derived.
    {
        const size_t base4 = (size_t)b0 * MAXN / 4;
        int4* __restrict__ gsrc = reinterpret_cast<int4*>(out) + base4;
        int4* __restrict__ gdst = reinterpret_cast<int4*>(out + (size_t)NTOT * MAXN) + base4;
        const int4* f4 = reinterpret_cast<const int4*>(&fin[0][0]);
        #pragma unroll
        for (int k = 0; k < 4; ++k) {
            const int flat = k * 256 + tid;      // flat int4 index 0..1023
            const int4 v = f4[flat];
            const int row = b0 + (flat >> 2);    // 4 int4s per output row
            int4 d;
            d.x = (v.x >= 0) ? row : -1;
            d.y = (v.y >= 0) ? row : -1;
            d.z = (v.z >= 0) ? row : -1;
            d.w = (v.w >= 0) ? row : -1;
            gsrc[flat] = v;
            gdst[flat] = d;
        }
    }
}

extern "C" void kernel_launch(void* const* d_in, const int* in_sizes, int n_in,
                              void* d_out, int out_size, void* d_ws, size_t ws_size,
                              hipStream_t stream) {
    const float* pos = (const float*)d_in[0];
    int* out = (int*)d_out;
    tgn_edges_kernel<<<NTOT / NPB, 256, 0, stream>>>(pos, out);
}